// Round 12
// baseline (727.951 us; speedup 1.0000x reference)
//
#include <hip/hip_runtime.h>
#include <hip/hip_bf16.h>
#include <cmath>

#define T_STEPS 16
#define BATCH   512
#define N_IN    3072
#define S1      256
#define S2      256
#define S3      128
#define NEXP    8
#define M_ROWS  (T_STEPS * BATCH)   // 8192
#define MT_ALL  (M_ROWS / 32)       // 256 m-tiles

typedef int v4i  __attribute__((ext_vector_type(4)));
typedef int v16i __attribute__((ext_vector_type(16)));
typedef unsigned long long u64;
typedef unsigned int uint32;

// ---------------------------------------------------------------------------
// pack binary fp32 x -> 1 bit/elem, TRANSPOSED: bitsT[kw][m'], m' = b*16+t.
// 3 MB total -> L2-resident on every XCD (the R11 i8-A materialization cost
// 162 MB HBM; bits cost 24 MB total).
// ---------------------------------------------------------------------------
__global__ __launch_bounds__(256) void pack_x_bits(
    const float* __restrict__ x, u64* __restrict__ bitsT)
{
    int gid = blockIdx.x * 256 + threadIdx.x;
    float v = x[gid];
    u64 m = __ballot(v >= 0.5f);
    if ((threadIdx.x & 63) == 0) {
        int tb = gid / N_IN;                 // t*512 + b
        int k  = gid - tb * N_IN;
        int t  = tb >> 9;
        int b  = tb & 511;
        bitsT[(size_t)(k >> 6) * M_ROWS + (b * 16 + t)] = m;
    }
}

// ---------------------------------------------------------------------------
// Weight digitize -> MFMA fragment tiles. B-row gr = o*32 + e*4 + limb.
// Bf[kb][nt=o][lane16][16], lane16 = (e*4+limb) + 32*qd, k = kb*32+qd*16+byte.
// ---------------------------------------------------------------------------
template<int S, int K>
__global__ __launch_bounds__(256) void digitize_w_frag(
    const float* __restrict__ W, char* __restrict__ Bf)
{
    constexpr int LOGS = (S == 256) ? 8 : 7;
    int t = blockIdx.x * 256 + threadIdx.x;   // chunks = 2*S*K
    int lane16 = t & 63;
    int o  = (t >> 6) & (S - 1);
    int kb = t >> (6 + LOGS);
    int r  = lane16 & 31;
    int qd = lane16 >> 5;
    int e    = r >> 2;
    int limb = r & 3;
    int k0 = kb * 32 + qd * 16;

    const float4* Wp = (const float4*)(W + ((size_t)e * S + o) * K + k0);
    char out[16];
    #pragma unroll
    for (int f4 = 0; f4 < 4; ++f4) {
        float4 w = Wp[f4];
        float ws[4] = {w.x, w.y, w.z, w.w};
        #pragma unroll
        for (int c = 0; c < 4; ++c) {
            long long q = llrint((double)ws[c] * 4294967296.0);
            int d = 0;
            #pragma unroll
            for (int l = 0; l < 4; ++l) {
                int dl = (int)((q + 128) & 255) - 128;
                q = (q - dl) >> 8;
                if (l == limb) d = dl;
            }
            out[f4 * 4 + c] = (char)d;
        }
    }
    *(v4i*)(Bf + (size_t)t * 16) = *(v4i*)out;
}

// ---------------------------------------------------------------------------
// Fused expert-GEMM + limb recombine + LIF + gated combine + mean.
// Block 256(m') x 128(B-rows): 4 waves stacked in m, wave tile 64x128
// (acc 2x4 v16i = 128 AGPR -> launch_bounds(256,2)). All waves share
// identical B addresses (L1 x4). Unpack VALU amortized over 2x MFMA
// vs R10 (R10: VALU 52% > MFMA 42% -- issue-saturated, rebalance).
// A: ABITS ? transposed bit rows (L2-resident 3 MB) : counts frag tiles.
// B depth-1 prefetch; A-bits depth-2. 1-D grid, XCD swizzle on nblk.
// ---------------------------------------------------------------------------
template<int K, int S, int SHIFT, bool ABITS, bool WRITEC, int NBLK>
__global__ __launch_bounds__(256, 2) void fused_stage(
    const void* __restrict__ Ap, const char* __restrict__ Bf,
    const float* __restrict__ g, char* __restrict__ Cf,
    float* __restrict__ Mean)
{
    constexpr int KI = K / 64;
    constexpr int NT = S;                    // 32-row n-tiles in Bf
    constexpr int NS = NBLK / 8;
    __shared__ double hs[256][32];           // 64 KB

    const int tid  = threadIdx.x;
    const int lane = tid & 63;
    const int w    = tid >> 6;
    const int col  = lane & 31;
    const int qd   = lane >> 5;
    const int wm   = w * 64;

    const int id   = blockIdx.x;
    const int nblk = (id & 7) * NS + ((id >> 3) % NS);
    const int mblk = id / NBLK;
    const int m0   = mblk * 256;

    const char* Bbase = Bf + ((size_t)(nblk * 4) * 64 + lane) * 16;

    v16i acc[2][4];
    #pragma unroll
    for (int i = 0; i < 2; ++i)
        #pragma unroll
        for (int j = 0; j < 4; ++j)
            #pragma unroll
            for (int r = 0; r < 16; ++r) acc[i][j][r] = 0;

    auto loadB = [&](int kb, int jj) -> v4i {
        return *(const v4i*)(Bbase + ((size_t)kb * NT + jj) * 1024);
    };

    v4i Bb[2][8];
    #pragma unroll
    for (int ks = 0; ks < 2; ++ks)
        #pragma unroll
        for (int jj = 0; jj < 4; ++jj)
            Bb[0][ks * 4 + jj] = loadB(ks, jj);

    if constexpr (ABITS) {
        const u64* AT = (const u64*)Ap + (m0 + wm + col);
        const int sh16 = qd * 16;
        auto unpack16 = [&](uint32 dw) -> v4i {
            uint32 w16 = dw >> sh16;
            v4i d;
            #pragma unroll
            for (int c = 0; c < 4; ++c)
                d[c] = (int)((((w16 >> (4 * c)) & 0xFu) * 0x00204081u) & 0x01010101u);
            return d;
        };
        u64 a0b[3], a1b[3];
        #pragma unroll
        for (int s = 0; s < 2; ++s) {
            a0b[s] = AT[(size_t)s * M_ROWS];
            a1b[s] = AT[(size_t)s * M_ROWS + 32];
        }
        #pragma unroll
        for (int it = 0; it < KI; ++it) {
            const int cur = it & 1;          // B slot
            const int pfB = (it + 1) & 1;
            const int itB = (it + 1 < KI) ? it + 1 : KI - 1;
            const int c3  = it % 3;          // bits slot
            const int p3  = (it + 2) % 3;
            const int itA = (it + 2 < KI) ? it + 2 : KI - 1;
            #pragma unroll
            for (int ks = 0; ks < 2; ++ks)
                #pragma unroll
                for (int jj = 0; jj < 4; ++jj)
                    Bb[pfB][ks * 4 + jj] = loadB(itB * 2 + ks, jj);
            a0b[p3] = AT[(size_t)itA * M_ROWS];
            a1b[p3] = AT[(size_t)itA * M_ROWS + 32];
            #pragma unroll
            for (int ks = 0; ks < 2; ++ks) {
                uint32 dw0 = ks ? (uint32)(a0b[c3] >> 32) : (uint32)a0b[c3];
                uint32 dw1 = ks ? (uint32)(a1b[c3] >> 32) : (uint32)a1b[c3];
                v4i af0 = unpack16(dw0);
                v4i af1 = unpack16(dw1);
                #pragma unroll
                for (int jj = 0; jj < 4; ++jj) {
                    acc[0][jj] = __builtin_amdgcn_mfma_i32_32x32x32_i8(af0, Bb[cur][ks*4+jj], acc[0][jj], 0,0,0);
                    acc[1][jj] = __builtin_amdgcn_mfma_i32_32x32x32_i8(af1, Bb[cur][ks*4+jj], acc[1][jj], 0,0,0);
                }
            }
        }
    } else {
        const int mt0 = (m0 + wm) >> 5;
        const char* Abase = (const char*)Ap + ((size_t)mt0 * 64 + lane) * 16;
        auto loadA = [&](int kb, int ii) -> v4i {
            return *(const v4i*)(Abase + ((size_t)kb * MT_ALL + ii) * 1024);
        };
        v4i Ab[2][4];
        #pragma unroll
        for (int ks = 0; ks < 2; ++ks) {
            Ab[0][ks * 2 + 0] = loadA(ks, 0);
            Ab[0][ks * 2 + 1] = loadA(ks, 1);
        }
        #pragma unroll
        for (int it = 0; it < KI; ++it) {
            const int cur = it & 1;
            const int pf  = (it + 1) & 1;
            const int itp = (it + 1 < KI) ? it + 1 : KI - 1;
            #pragma unroll
            for (int ks = 0; ks < 2; ++ks) {
                Ab[pf][ks * 2 + 0] = loadA(itp * 2 + ks, 0);
                Ab[pf][ks * 2 + 1] = loadA(itp * 2 + ks, 1);
                #pragma unroll
                for (int jj = 0; jj < 4; ++jj)
                    Bb[pf][ks * 4 + jj] = loadB(itp * 2 + ks, jj);
            }
            #pragma unroll
            for (int ks = 0; ks < 2; ++ks) {
                #pragma unroll
                for (int jj = 0; jj < 4; ++jj) {
                    acc[0][jj] = __builtin_amdgcn_mfma_i32_32x32x32_i8(Ab[cur][ks*2+0], Bb[cur][ks*4+jj], acc[0][jj], 0,0,0);
                    acc[1][jj] = __builtin_amdgcn_mfma_i32_32x32x32_i8(Ab[cur][ks*2+1], Bb[cur][ks*4+jj], acc[1][jj], 0,0,0);
                }
            }
        }
    }

    // ---- limb recombine (exact, in double) -> LDS h tile ----
    const double sbase = 1.0 / (double)(1ll << SHIFT);
    const int limb = col & 3;
    const double lscale = (double)(1 << (8 * limb)) * sbase;
    #pragma unroll
    for (int j = 0; j < 4; ++j) {
        const int oe = j * 8 + (col >> 2);            // o_loc*8 + e
        #pragma unroll
        for (int i = 0; i < 2; ++i) {
            #pragma unroll
            for (int reg = 0; reg < 16; ++reg) {
                double d = (double)acc[i][j][reg] * lscale;
                d += __shfl_xor(d, 1);
                d += __shfl_xor(d, 2);
                if ((col & 3) == 0) {
                    int m = wm + i * 32 + (reg & 3) + 8 * (reg >> 2) + 4 * qd;
                    hs[m][oe] = d;
                }
            }
        }
    }
    __syncthreads();

    // ---- LIF scan: 512 items (16 b x 4 o x 8 e), 2 per thread ----
    double v0 = 0.0, v1 = 0.0;
    float ga0 = 0.0f, ga1 = 0.0f;
    const int e     = tid & 7;
    const float ge  = g[e];
    const int o_loc = (tid >> 3) & 3;
    const int oe    = o_loc * 8 + e;
    const int bl0   = tid >> 5;              // 0..7
    const int bl1   = bl0 + 8;               // 8..15
    const int og    = nblk * 4 + o_loc;
    const int bg0   = mblk * 16 + bl0;
    const int bg1   = mblk * 16 + bl1;
    const int kb_a   = og >> 5;
    const int qd_a   = (og >> 4) & 1;
    const int byte_a = og & 15;

    #pragma unroll
    for (int t = 0; t < T_STEPS; ++t) {
        double h0 = hs[bl0 * 16 + t][oe];
        double h1 = hs[bl1 * 16 + t][oe];
        double vv0 = v0 * 0.95 + h0;
        double vv1 = v1 * 0.95 + h1;
        int s0 = (vv0 >= 1.0) ? 1 : 0;
        int s1 = (vv1 >= 1.0) ? 1 : 0;
        v0 = vv0 - (double)s0;
        v1 = vv1 - (double)s1;
        float gs0 = ge * (float)s0;
        float gs1 = ge * (float)s1;
        gs0 += __shfl_xor(gs0, 1); gs0 += __shfl_xor(gs0, 2); gs0 += __shfl_xor(gs0, 4);
        gs1 += __shfl_xor(gs1, 1); gs1 += __shfl_xor(gs1, 2); gs1 += __shfl_xor(gs1, 4);
        ga0 += gs0;
        ga1 += gs1;
        if (WRITEC) {
            int c0 = s0, c1 = s1;
            c0 += __shfl_xor(c0, 1); c0 += __shfl_xor(c0, 2); c0 += __shfl_xor(c0, 4);
            c1 += __shfl_xor(c1, 1); c1 += __shfl_xor(c1, 2); c1 += __shfl_xor(c1, 4);
            if (e == 0) {
                int mp0 = bg0 * 16 + t;
                int mp1 = bg1 * 16 + t;
                Cf[(((size_t)kb_a * MT_ALL + (mp0 >> 5)) * 64 + ((mp0 & 31) + 32 * qd_a)) * 16 + byte_a] = (char)c0;
                Cf[(((size_t)kb_a * MT_ALL + (mp1 >> 5)) * 64 + ((mp1 & 31) + 32 * qd_a)) * 16 + byte_a] = (char)c1;
            }
        }
    }
    if (e == 0) {
        Mean[(size_t)bg0 * S + og] = ga0 * 0.0625f;
        Mean[(size_t)bg1 * S + og] = ga1 * 0.0625f;
    }
}

// ---------------------------------------------------------------------------
// ws layout (bytes):
//   AbitsT @ 0          : 3 MB   (48 x 8192 u64, transposed)
//   B1f    @ 3145728    : 24 MB
//   B2f    @ 28311552   :  2 MB
//   B3f    @ 30408704   :  1 MB
//   c1f    @ 31457280   :  2 MB  (frag-tile counts, K=256)
//   c2f    @ 33554432   :  2 MB
// ---------------------------------------------------------------------------
extern "C" void kernel_launch(void* const* d_in, const int* in_sizes, int n_in,
                              void* d_out, int out_size, void* d_ws, size_t ws_size,
                              hipStream_t stream) {
    const float* x  = (const float*)d_in[0];
    const float* W1 = (const float*)d_in[1];
    const float* W2 = (const float*)d_in[2];
    const float* W3 = (const float*)d_in[3];
    const float* g1 = (const float*)d_in[4];
    const float* g2 = (const float*)d_in[5];
    const float* g3 = (const float*)d_in[6];
    float* out = (float*)d_out;

    char* ws = (char*)d_ws;
    u64*  AbitsT = (u64*)ws;
    char* B1f    = ws + 3145728ull;
    char* B2f    = ws + 28311552ull;
    char* B3f    = ws + 30408704ull;
    char* c1f    = ws + 31457280ull;
    char* c2f    = ws + 33554432ull;

    dim3 blk(256);

    // --- precompute ---
    pack_x_bits<<<(M_ROWS * N_IN) / 256, blk, 0, stream>>>(x, AbitsT);
    digitize_w_frag<S1, N_IN><<<(2 * S1 * N_IN) / 256, blk, 0, stream>>>(W1, B1f);
    digitize_w_frag<S2, S1><<<(2 * S2 * S1) / 256, blk, 0, stream>>>(W2, B2f);
    digitize_w_frag<S3, S2><<<(2 * S3 * S2) / 256, blk, 0, stream>>>(W3, B3f);

    // --- three fused GEMM+LIF stages, XCD-swizzled 1-D grids ---
    // block tile 256m x 128n; grids: mblk=32, nblk = S*32/128
    fused_stage<N_IN, S1, 32, true,  true,  64><<<32 * 64, blk, 0, stream>>>(
        AbitsT, B1f, g1, c1f, out);
    fused_stage<S1,   S2, 35, false, true,  64><<<32 * 64, blk, 0, stream>>>(
        c1f, B2f, g2, c2f, out + BATCH * S1);
    fused_stage<S2,   S3, 35, false, false, 32><<<32 * 32, blk, 0, stream>>>(
        c2f, B3f, g3, nullptr, out + BATCH * (S1 + S2));
}